// Round 18
// baseline (396.552 us; speedup 1.0000x reference)
//
#include <hip/hip_runtime.h>
#include <stdint.h>

typedef unsigned short u16;
typedef __attribute__((ext_vector_type(8))) __bf16 bf16x8;
typedef __attribute__((ext_vector_type(4))) float f32x4;
typedef __attribute__((ext_vector_type(8))) u16 u16x8;

static __device__ __forceinline__ u16 f2bf(float f){
  uint32_t x = __builtin_bit_cast(uint32_t, f);
  x = (x + 0x7FFFu + ((x >> 16) & 1u)) >> 16;
  return (u16)x;
}
static __device__ __forceinline__ u16 f2bf_fast(float f){ // round-half-up (p>=0)
  uint32_t x = __builtin_bit_cast(uint32_t, f);
  return (u16)((x + 0x8000u) >> 16);
}
static __device__ __forceinline__ float bf2f(u16 h){
  uint32_t x = ((uint32_t)h) << 16;
  return __builtin_bit_cast(float, x);
}
static __device__ __forceinline__ f32x4 mfma16(bf16x8 a, bf16x8 b, f32x4 c){
  return __builtin_amdgcn_mfma_f32_16x16x32_bf16(a, b, c, 0, 0, 0);
}
// async global->LDS, 16B per lane; LDS dest = wave-uniform base + lane*16
static __device__ __forceinline__ void gload16(const void* g, void* l){
  __builtin_amdgcn_global_load_lds(
      (const __attribute__((address_space(1))) void*)(uintptr_t)g,
      (__attribute__((address_space(3))) void*)(uint32_t)(uintptr_t)l,
      16, 0, 0);
}

// ================================================================================
// k_prep — ALL prep work in one launch (block-range dispatch):
//  [0,1024)        DFT tables C=cos, S=sin (1024x1024 bf16)
//  [1024,4224)     x DOUBLE-fold transpose (real-DFT fold on BOTH n and d)
//  [4224,8320)     wq,wk,wv,wo transpose->bf16 (1024 blocks each)
//  [8320,12416)    wuv transpose + u/v 16-col interleave
//  [12416,14464)   wout transpose (2048x1024 -> 1024x2048)
//  [14464,14476)   bias concat (bq|bk|bv)
// ================================================================================
__global__ __launch_bounds__(256) void k_prep(
    const float* __restrict__ x,  const float* __restrict__ wq,
    const float* __restrict__ wk, const float* __restrict__ wv,
    const float* __restrict__ wo, const float* __restrict__ wuv,
    const float* __restrict__ wout,
    const float* __restrict__ bq, const float* __restrict__ bk,
    const float* __restrict__ bv,
    u16* __restrict__ Cb, u16* __restrict__ Sb,
    u16* __restrict__ xP, u16* __restrict__ xM,
    u16* __restrict__ wqkvt, u16* __restrict__ wot, u16* __restrict__ wuvt,
    u16* __restrict__ woutt, float* __restrict__ bqkv)
{
  int bid = blockIdx.x;
  int t = threadIdx.x;
  __shared__ float tA[32][33];
  __shared__ float tB[32][33];
  __shared__ float tC[32][33];
  __shared__ float tD[32][33];
  if (bid < 1024){                       // ---- twiddle tables ----
    int n = bid, m0 = t * 4;
    #pragma unroll
    for (int i = 0; i < 4; ++i){
      int m = m0 + i;
      int ph = (n * m) & 1023;
      float a = (float)ph * (1.0f / 512.0f);
      int idx = n * 1024 + m;
      Cb[idx] = f2bf(cospif(a)); Sb[idx] = f2bf(sinpif(a));
    }
    return;
  }
  bid -= 1024;
  if (bid >= 13440){                     // ---- bias concat (12 blocks) ----
    int i = (bid - 13440) * 256 + t;     // 0..3071
    bqkv[i] = i < 1024 ? bq[i] : (i < 2048 ? bk[i - 1024] : bv[i - 2048]);
    return;
  }
  int lx = t & 31, ly = t >> 5;
  if (bid < 3200){                       // ---- x double-fold transpose ----
    int z = bid / 400, rem = bid % 400;
    int dt = rem / 20, nt = rem % 20;    // output tile coords (d, n)
    int d0 = dt * 32, n0 = nt * 32;
    const float* ip = x + ((int64_t)z << 20);
    #pragma unroll
    for (int k8 = 0; k8 < 32; k8 += 8)
      tA[ly + k8][lx] = ip[(int64_t)(n0 + ly + k8) * 1024 + d0 + lx];
    if (dt <= 15){
      #pragma unroll
      for (int k8 = 0; k8 < 32; k8 += 8){
        float v = 0.f;
        if (!(d0 == 0 && lx == 31))
          v = ip[(int64_t)(n0 + ly + k8) * 1024 + (993 - d0 + lx)];
        tB[ly + k8][lx] = v;
      }
    }
    if (nt <= 15){
      #pragma unroll
      for (int k8 = 0; k8 < 32; k8 += 8){
        float v = 0.f;
        if (!(n0 == 0 && (ly + k8) == 31))
          v = ip[(int64_t)(993 - n0 + ly + k8) * 1024 + d0 + lx];
        tC[ly + k8][lx] = v;
      }
    }
    if (dt <= 15 && nt <= 15){
      #pragma unroll
      for (int k8 = 0; k8 < 32; k8 += 8){
        float v = 0.f;
        if (!(n0 == 0 && (ly + k8) == 31) && !(d0 == 0 && lx == 31))
          v = ip[(int64_t)(993 - n0 + ly + k8) * 1024 + (993 - d0 + lx)];
        tD[ly + k8][lx] = v;
      }
    }
    __syncthreads();
    u16* Pp = xP + (int64_t)z * 409600 + n0 + lx;
    u16* Mp = xM + (int64_t)z * 409600 + n0 + lx;
    #pragma unroll
    for (int k8 = 0; k8 < 32; k8 += 8){
      int dj = ly + k8;
      int d = d0 + dj, n = n0 + lx;
      bool dv = (d >= 1 && d <= 511), nv = (n >= 1 && n <= 511);
      float base = tA[lx][dj];
      float dm = dv ? tB[lx][31 - dj] : 0.f;
      float nm = nv ? tC[31 - lx][dj] : 0.f;
      float bm = (dv && nv) ? tD[31 - lx][31 - dj] : 0.f;
      float pv = base + dm + nm + bm;
      float mv = base - dm - nm + bm;
      if (d > 512 || n > 512){ pv = 0.f; mv = 0.f; }
      Pp[(int64_t)d * 640] = f2bf(pv);
      Mp[(int64_t)d * 640] = f2bf(mv);
    }
    return;
  }
  // ---- transpose jobs ----
  const float* in; u16* out; int Cc, R, bx, by;
  int64_t outOff = 0;
  bool uvperm = false;
  if (bid < 7296){                       // wq/wk/wv/wo
    int j = (bid - 3200) >> 10, tile = (bid - 3200) & 1023;
    const float* srcs[4] = {wq, wk, wv, wo};
    in = srcs[j]; Cc = 1024; R = 1024;
    if (j < 3){ out = wqkvt; outOff = (int64_t)j << 20; }
    else      { out = wot; }
    bx = tile & 31; by = tile >> 5;
  } else if (bid < 11392){               // wuv interleave (16-col groups)
    int tile = bid - 7296;
    in = wuv; out = wuvt; Cc = 4096; R = 1024; uvperm = true;
    bx = tile & 127; by = tile >> 7;
  } else {                               // wout
    int tile = bid - 11392;
    in = wout; out = woutt; Cc = 1024; R = 2048;
    bx = tile & 31; by = tile >> 5;
  }
  int tc = bx * 32, tr = by * 32;
  #pragma unroll
  for (int i = 0; i < 32; i += 8)
    tA[ly + i][lx] = in[(int64_t)(tr + ly + i) * Cc + tc + lx];
  __syncthreads();
  if (uvperm){
    #pragma unroll
    for (int i = 0; i < 32; i += 8){
      int c = tc + ly + i;
      int pr = (c < 2048) ? ((c >> 4) * 32 + (c & 15))
                          : (((c - 2048) >> 4) * 32 + 16 + ((c - 2048) & 15));
      out[(int64_t)pr * 1024 + tr + lx] = f2bf(tA[lx][ly + i]);
    }
  } else {
    u16* op = out + outOff;
    #pragma unroll
    for (int i = 0; i < 32; i += 8)
      op[(int64_t)(tc + ly + i) * R + tr + lx] = f2bf(tA[lx][ly + i]);
  }
}

// ---------------- RMSNorm (row=1024 f32) -> bf16 --------------------------------
__global__ __launch_bounds__(256) void k_rmsnorm(const float* __restrict__ x,
                                                 const float* __restrict__ sc,
                                                 u16* __restrict__ out){
  int r = blockIdx.x;
  const float4* px = (const float4*)(x + (int64_t)r * 1024);
  float4 v = px[threadIdx.x];
  float ss = v.x*v.x + v.y*v.y + v.z*v.z + v.w*v.w;
  #pragma unroll
  for (int o = 1; o < 64; o <<= 1) ss += __shfl_xor(ss, o);
  __shared__ float red[4];
  if ((threadIdx.x & 63) == 0) red[threadIdx.x >> 6] = ss;
  __syncthreads();
  float tot = red[0] + red[1] + red[2] + red[3];
  float rs = rsqrtf(tot * (1.0f / 1024.0f) + 1e-5f);
  float4 s4 = ((const float4*)sc)[threadIdx.x];
  ushort4 ov;
  ov.x = f2bf(v.x * rs * s4.x); ov.y = f2bf(v.y * rs * s4.y);
  ov.z = f2bf(v.z * rs * s4.z); ov.w = f2bf(v.w * rs * s4.w);
  ((ushort4*)(out + (int64_t)r * 1024))[threadIdx.x] = ov;
}

// ------- FFT finalize + fused RMSNorm: dual-fold (f_n rows AND f_d cols) --------
__global__ __launch_bounds__(256) void k_fftfin(const u16* __restrict__ Uw,
                                                const float* __restrict__ sc,
                                                float* __restrict__ Y,
                                                u16* __restrict__ xn){
  int row = blockIdx.x;            // b*1024 + k  (k = f_n)
  int b = row >> 10, k = row & 1023;
  int kp = (k <= 512) ? k : 1024 - k;
  float sm = (k <= 512) ? 1.0f : -1.0f;
  const u16* ub = Uw + (int64_t)b * 819200 + (int64_t)kp * 640;
  const u16* wb = ub + 640 * 640;
  int c0 = threadIdx.x * 4;
  float y[4];
  #pragma unroll
  for (int i = 0; i < 4; ++i){
    int c = c0 + i;
    int tp = (c <= 512) ? c : 1024 - c;
    float st = (c <= 512) ? sm : -sm;
    y[i] = bf2f(ub[tp]) - st * bf2f(wb[tp]);
  }
  float ss = y[0]*y[0] + y[1]*y[1] + y[2]*y[2] + y[3]*y[3];
  #pragma unroll
  for (int o = 1; o < 64; o <<= 1) ss += __shfl_xor(ss, o);
  __shared__ float red[4];
  if ((threadIdx.x & 63) == 0) red[threadIdx.x >> 6] = ss;
  __syncthreads();
  float tot = red[0] + red[1] + red[2] + red[3];
  float rs = rsqrtf(tot * (1.0f / 1024.0f) + 1e-5f);
  float4 s4 = ((const float4*)sc)[threadIdx.x];
  float4 yo; yo.x = y[0]; yo.y = y[1]; yo.z = y[2]; yo.w = y[3];
  ((float4*)(Y + (int64_t)row * 1024))[threadIdx.x] = yo;
  ushort4 ov;
  ov.x = f2bf(y[0] * rs * s4.x); ov.y = f2bf(y[1] * rs * s4.y);
  ov.z = f2bf(y[2] * rs * s4.z); ov.w = f2bf(y[3] * rs * s4.w);
  ((ushort4*)(xn + (int64_t)row * 1024))[threadIdx.x] = ov;
}

// ================================================================================
// bf16 GEMM — (MR*32) x 128 tile, BK=32, 256 thr (4 waves, 2x2 of (MR*16)x64).
// MR=4: proven m97 geometry, 32KB LDS dbuf, 4 blocks/CU.
// MR=8: 256x128 register-reuse tile (12 LDS reads : 32 MFMAs/wave), 48KB LDS,
//       ~2 waves/SIMD — used where the LDS-BW cap dominates (uv, wout GEMMs).
// Bijective XCD swizzle (m204) + L2 supertile decode (GW=16/8/gx).
// COLCHUNK: column-major decode (FFT1). Zero-conflict row-pair LDS swizzle.
// Row-region operand select. Optional SiLU epilogue; optional fused V-transpose.
// ================================================================================
template<int MR, bool SILU, bool COLCHUNK>
__global__ __launch_bounds__(256, (MR == 8) ? 2 : 4) void k_gemm4(
    const u16* __restrict__ A0, const u16* __restrict__ A1,
    const u16* __restrict__ B0, const u16* __restrict__ B1,
    void* Cout, const float* __restrict__ bias, const float* resid,
    u16* __restrict__ vtbuf, int vtn0,
    int nkt, int rowSplit, int lda, int ldb, int ldc,
    int64_t aB, int64_t bB, int64_t cB, int outBf16)
{
  constexpr int BM = MR * 32;
  constexpr int ABUF = BM * 64;          // A K-tile bytes (BM x 32 x 2B)
  constexpr int BUFB = ABUF + 8192;      // + B K-tile (128 x 32 x 2B)
  constexpr int APASS = ABUF / 4096;     // A gloads per thread (2 or 4)
  __shared__ char smem[2 * BUFB];

  int z = blockIdx.z;
  // bijective XCD swizzle (m204): works for any nwg
  int nwg = gridDim.x * gridDim.y;
  int bid = blockIdx.y * gridDim.x + blockIdx.x;
  int q = nwg >> 3, r = nwg & 7, xc = bid & 7, off = bid >> 3;
  int sw = (xc < r ? xc * (q + 1) : r * (q + 1) + (xc - r) * q) + off;
  int bx, by;
  if (COLCHUNK){
    bx = sw / gridDim.y; by = sw % gridDim.y;
  } else {
    int gx = gridDim.x;
    int GW = ((gx & 15) == 0) ? 16 : (((gx & 7) == 0) ? 8 : gx);
    int gsz = GW * gridDim.y;
    int grp = sw / gsz, rem = sw % gsz;
    bx = grp * GW + rem % GW;
    by = rem / GW;
  }

  int tm = by * BM, tn = bx * 128;
  int tid = threadIdx.x;
  int lane = tid & 63, w = tid >> 6;
  int lr = lane & 15, lg = lane >> 4;
  int wOffM = (w >> 1) * (BM / 2), wOffN = (w & 1) * 64;

  const u16* Ap = ((tm < rowSplit) ? A0 : A1) + (int64_t)z * aB;
  const u16* Bp = ((tm < rowSplit) ? B0 : B1) + (int64_t)z * bB;
  int64_t cOff = (int64_t)z * cB;

  // staging decode: APASS A gloads + 2 B gloads of 16B per thread per K-tile
  const u16* pA[APASS];
  const u16* pB[2];
  #pragma unroll
  for (int p = 0; p < APASS; ++p){
    int D = tid * 16 + p * 4096, line = D >> 7, sp = ((D >> 4) & 7) ^ (line & 7);
    int rr = line * 2 + (sp >> 2), kg = sp & 3;
    pA[p] = Ap + (int64_t)(tm + rr) * lda + kg * 8;
  }
  #pragma unroll
  for (int p = 0; p < 2; ++p){
    int D = tid * 16 + p * 4096, line = D >> 7, sp = ((D >> 4) & 7) ^ (line & 7);
    int rr = line * 2 + (sp >> 2), kg = sp & 3;
    pB[p] = Bp + (int64_t)(tn + rr) * ldb + kg * 8;
  }

  int slotR = (lg + ((lr & 1) << 2)) ^ ((lr >> 1) & 7);
  int aRB = ((wOffM >> 1) + (lr >> 1)) * 128 + slotR * 16;
  int bRB = ((wOffN >> 1) + (lr >> 1)) * 128 + slotR * 16;

  const f32x4 fz = {0.f, 0.f, 0.f, 0.f};
  f32x4 acc[MR][4];
  #pragma unroll
  for (int i = 0; i < MR; ++i)
    #pragma unroll
    for (int j = 0; j < 4; ++j) acc[i][j] = fz;

  auto STAGE = [&](int kt, int bf){
    int k0 = kt * 32;
    char* d = smem + bf * BUFB + tid * 16;
    #pragma unroll
    for (int p = 0; p < APASS; ++p) gload16(pA[p] + k0, d + p * 4096);
    #pragma unroll
    for (int p = 0; p < 2; ++p) gload16(pB[p] + k0, d + ABUF + p * 4096);
  };
  auto COMPUTE = [&](const char* Ab){
    const char* Bb = Ab + ABUF;
    bf16x8 af[MR], bfr[4];
    #pragma unroll
    for (int i = 0; i < MR; ++i) af[i] = *(const bf16x8*)(Ab + aRB + i * 1024);
    #pragma unroll
    for (int j = 0; j < 4; ++j) bfr[j] = *(const bf16x8*)(Bb + bRB + j * 1024);
    #pragma unroll
    for (int i = 0; i < MR; ++i)
      #pragma unroll
      for (int j = 0; j < 4; ++j)
        acc[i][j] = mfma16(af[i], bfr[j], acc[i][j]);
  };

  STAGE(0, 0);
  __syncthreads();
  for (int kt = 0; kt < nkt; kt += 2){     // nkt always even
    STAGE(kt + 1, 1);
    COMPUTE(smem);
    __syncthreads();
    if (kt + 2 < nkt) STAGE(kt + 2, 0);
    COMPUTE(smem + BUFB);
    __syncthreads();
  }

  // ---- epilogue: C frag layout row=(lane>>4)*4+jj, col=lane&15 ----
  if constexpr (SILU){
    int colBase = ((tn + wOffN) >> 1) + lr;
    #pragma unroll
    for (int i = 0; i < MR; ++i){
      #pragma unroll
      for (int jj = 0; jj < 4; ++jj){
        int row = tm + wOffM + i * 16 + lg * 4 + jj;
        #pragma unroll
        for (int jp = 0; jp < 2; ++jp){
          float u = acc[i][jp * 2][jj], v = acc[i][jp * 2 + 1][jj];
          float s = u / (1.0f + __expf(-u));
          ((u16*)Cout)[(int64_t)row * ldc + colBase + jp * 16] = f2bf(s * v);
        }
      }
    }
    return;
  }
  if (vtbuf && tn >= vtn0){
    // V region of qkv: write transposed vt[b*16+h][d][key], 4 keys per ushort4
    int b = tm >> 10;
    int key0 = (tm & 1023) + wOffM + lg * 4;
    #pragma unroll
    for (int j = 0; j < 4; ++j){
      int col = tn + wOffN + j * 16 + lr;
      int hv = (col - 2048) >> 6, d = (col - 2048) & 63;
      float badd = bias ? bias[col] : 0.0f;
      u16* vb = vtbuf + ((int64_t)(b * 16 + hv) << 16) + d * 1024;
      #pragma unroll
      for (int i = 0; i < MR; ++i){
        ushort4 pk;
        pk.x = f2bf(acc[i][j][0] + badd);
        pk.y = f2bf(acc[i][j][1] + badd);
        pk.z = f2bf(acc[i][j][2] + badd);
        pk.w = f2bf(acc[i][j][3] + badd);
        *(ushort4*)(vb + key0 + i * 16) = pk;
      }
    }
    return;
  }
  #pragma unroll
  for (int i = 0; i < MR; ++i){
    #pragma unroll
    for (int j = 0; j < 4; ++j){
      int col = tn + wOffN + j * 16 + lr;
      float badd = bias ? bias[col] : 0.0f;
      #pragma unroll
      for (int jj = 0; jj < 4; ++jj){
        int row = tm + wOffM + i * 16 + lg * 4 + jj;
        int64_t idx = cOff + (int64_t)row * ldc + col;
        float v = acc[i][j][jj] + badd;
        if (resid) v += resid[idx];
        if (outBf16) ((u16*)Cout)[idx] = f2bf(v);
        else         ((float*)Cout)[idx] = v;
      }
    }
  }
}

// ---------------- flash attention v4: QBLK=256, 8 waves, static-max softmax -----
// grid (4 q-tiles of 256, 128 b*h), 512 thr; wave w owns 32 q-rows. 2 blocks/CU.
__global__ __launch_bounds__(512, 4) void k_attn2(const u16* __restrict__ qkv,
                                                  const u16* __restrict__ vt,
                                                  u16* __restrict__ O){
  __shared__ u16 Ks[2][4096];    // 16KB  [key][d] swizzled
  __shared__ u16 Vts[2][4096];   // 16KB  [d][key] swizzled
  __shared__ u16 Pl[8][2304];    // 36KB  per-wave P [32][72]
  int bh = blockIdx.y; int b = bh >> 4, h = bh & 15;
  int qt = blockIdx.x;
  int t = threadIdx.x, w = t >> 6, lane = t & 63, lr = lane & 15, lg = lane >> 4;
  int sr = t >> 3, sl = t & 7;           // staging: row 0..63, 16B slot
  int swz = (sl ^ (sr & 7)) * 8;         // swizzled k/key element offset

  const u16* kg = qkv + (int64_t)b * 1024 * 3072 + 1024 + h * 64;
  const u16* vg = vt + (int64_t)bh * 65536;

  const u16* qrow = qkv + (int64_t)(b * 1024 + qt * 256 + w * 32 + lr) * 3072 + h * 64;
  bf16x8 aq[2][2];
  #pragma unroll
  for (int m = 0; m < 2; ++m)
    #pragma unroll
    for (int kc = 0; kc < 2; ++kc)
      aq[m][kc] = *(const bf16x8*)(qrow + (int64_t)m * 16 * 3072 + kc * 32 + lg * 8);

  const f32x4 fz = {0.f, 0.f, 0.f, 0.f};
  f32x4 o_[2][4];
  float lj[2][4];
  #pragma unroll
  for (int m = 0; m < 2; ++m){
    #pragma unroll
    for (int d = 0; d < 4; ++d) o_[m][d] = fz;
    #pragma unroll
    for (int j = 0; j < 4; ++j) lj[m][j] = 0.f;
  }

  #define STAGE(ktile, bn) do {                                                   \
    gload16(kg + (int64_t)((ktile) * 64 + sr) * 3072 + swz,                       \
            (char*)Ks + (bn) * 8192 + t * 16);                                    \
    gload16(vg + (int64_t)sr * 1024 + (ktile) * 64 + swz,                         \
            (char*)Vts + (bn) * 8192 + t * 16);                                   \
  } while (0)

  STAGE(0, 0);
  __syncthreads();
  int buf = 0;
  int lsw = lr & 7;

  const float CSC = 0.1803368801111204f;  // log2(e)/8
  const float MSH = 8.656170245333781f;   // 6*log2(e): static shift

  #pragma unroll 1
  for (int kt = 0; kt < 16; ++kt){
    if (kt < 15) STAGE(kt + 1, buf ^ 1);

    f32x4 s[2][4];
    #pragma unroll
    for (int m = 0; m < 2; ++m)
      #pragma unroll
      for (int n = 0; n < 4; ++n) s[m][n] = fz;
    #pragma unroll
    for (int n = 0; n < 4; ++n){
      #pragma unroll
      for (int kc = 0; kc < 2; ++kc){
        bf16x8 kb = *(const bf16x8*)&Ks[buf][(n * 16 + lr) * 64 + (((kc * 4 + lg) ^ lsw) * 8)];
        s[0][n] = mfma16(aq[0][kc], kb, s[0][n]);
        s[1][n] = mfma16(aq[1][kc], kb, s[1][n]);
      }
    }

    #pragma unroll
    for (int m = 0; m < 2; ++m){
      #pragma unroll
      for (int j = 0; j < 4; ++j){
        float p0 = exp2f(fmaf(s[m][0][j], CSC, -MSH));
        float p1 = exp2f(fmaf(s[m][1][j], CSC, -MSH));
        float p2 = exp2f(fmaf(s[m][2][j], CSC, -MSH));
        float p3 = exp2f(fmaf(s[m][3][j], CSC, -MSH));
        lj[m][j] += (p0 + p1) + (p2 + p3);
        u16* pb = &Pl[w][(m * 16 + lg * 4 + j) * 72 + lr];
        pb[0]  = f2bf_fast(p0); pb[16] = f2bf_fast(p1);
        pb[32] = f2bf_fast(p2); pb[48] = f2bf_fast(p3);
      }
    }
    asm volatile("s_waitcnt lgkmcnt(0)" ::: "memory");
    __builtin_amdgcn_sched_barrier(0);

    #pragma unroll
    for (int kc = 0; kc < 2; ++kc){
      bf16x8 pa0 = *(const bf16x8*)&Pl[w][(lr) * 72 + kc * 32 + lg * 8];
      bf16x8 pa1 = *(const bf16x8*)&Pl[w][(16 + lr) * 72 + kc * 32 + lg * 8];
      #pragma unroll
      for (int dt = 0; dt < 4; ++dt){
        bf16x8 vb = *(const bf16x8*)&Vts[buf][(dt * 16 + lr) * 64 + (((kc * 4 + lg) ^ lsw) * 8)];
        o_[0][dt] = mfma16(pa0, vb, o_[0][dt]);
        o_[1][dt] = mfma16(pa1, vb, o_[1][dt]);
      }
    }
    __syncthreads();
    buf ^= 1;
  }
  #undef STAGE

  u16* obase = O + (int64_t)(b * 1024 + qt * 256 + w * 32) * 1024 + h * 64;
  #pragma unroll
  for (int m = 0; m < 2; ++m){
    #pragma unroll
    for (int j = 0; j < 4; ++j){
      float l = lj[m][j];
      l += __shfl_xor(l, 1); l += __shfl_xor(l, 2);
      l += __shfl_xor(l, 4); l += __shfl_xor(l, 8);
      float inv = 1.0f / l;
      int q = m * 16 + lg * 4 + j;
      #pragma unroll
      for (int dt = 0; dt < 4; ++dt)
        obase[(int64_t)q * 1024 + dt * 16 + lr] = f2bf(o_[m][dt][j] * inv);
    }
  }
}

// ================================================================================
extern "C" void kernel_launch(void* const* d_in, const int* in_sizes, int n_in,
                              void* d_out, int out_size, void* d_ws, size_t ws_size,
                              hipStream_t stream)
{
  (void)in_sizes; (void)n_in; (void)out_size; (void)ws_size;
  const float* x    = (const float*)d_in[0];
  const float* ans  = (const float*)d_in[1];
  const float* fns  = (const float*)d_in[2];
  const float* wq   = (const float*)d_in[3];
  const float* bq   = (const float*)d_in[4];
  const float* wk   = (const float*)d_in[5];
  const float* bk   = (const float*)d_in[6];
  const float* wv   = (const float*)d_in[7];
  const float* bvv  = (const float*)d_in[8];
  const float* wo   = (const float*)d_in[9];
  const float* bo   = (const float*)d_in[10];
  const float* wuv  = (const float*)d_in[11];
  const float* wout = (const float*)d_in[12];

  char* ws = (char*)d_ws;
  const size_t MB = 1u << 20;
  const int64_t XPB = 409600;                    // per-batch P/M elems (640x640)
  const int64_t FB2 = (int64_t)1280 * 640;       // per-batch Xcs/Uw (folded cols)
  const int BIG = 1 << 30;
  // arena (peak ~128.01 MB, lifetime-based reuse)
  u16*  xP    = (u16*)(ws + 0 * MB);      // 6.6MB even-even fold, dies after FFT1
  u16*  xM    = (u16*)(ws + 7 * MB);      // 6.6MB odd-odd fold, dies after FFT1
  u16*  Xcs   = (u16*)(ws + 14 * MB);     // 13.1MB folded FFT1 out, dies at FFT2
  u16*  Uw    = (u16*)(ws + 28 * MB);     // 13.1MB FFT2 out, dies at fftfin
  u16*  xn    = (u16*)(ws + 56 * MB);     // 16MB  RMSNorm#1 out (fused in fftfin)
  u16*  qkv   = (u16*)(ws + 0 * MB);      // 48MB  (reuses xP/xM/Xcs/Uw post-fftfin)
  u16*  vtg   = (u16*)(ws + 72 * MB);     // 16MB  V^T (written by qkv GEMM)
  u16*  Obuf  = (u16*)(ws + 88 * MB);     // 16MB  (attn out)
  u16*  xn2   = (u16*)(ws + 0 * MB);      // 16MB  (after wo; qkv dead)
  u16*  g     = (u16*)(ws + 16 * MB);     // 32MB
  u16*  Cb    = (u16*)(ws + 104 * MB);    // 2MB
  u16*  Sb    = (u16*)(ws + 106 * MB);    // 2MB
  u16*  wqkvt = (u16*)(ws + 108 * MB);    // 6MB
  u16*  wot   = (u16*)(ws + 114 * MB);    // 2MB
  u16*  wuvt  = (u16*)(ws + 116 * MB);    // 8MB  (interleaved u/v layout)
  u16*  woutt = (u16*)(ws + 124 * MB);    // 4MB
  float* bqkv = (float*)(ws + 128 * MB);  // 12KB
  float* outF = (float*)d_out;            // Y lives in d_out (f32 residual)

  // ---- fused prep (tables + x double-fold + weight transposes + bias) ----
  k_prep<<<dim3(14476), 256, 0, stream>>>(x, wq, wk, wv, wo, wuv, wout,
      bq, bk, bvv, Cb, Sb, xP, xM, wqkvt, wot, wuvt, woutt, bqkv);

  // ---- FFT stage 1 (both axes folded): Xcs[b][1280][640], K=640 ----
  k_gemm4<4, false, true><<<dim3(5, 10, 8), 256, 0, stream>>>(
      Cb, Sb - 640 * 1024, xP, xM, Xcs, nullptr, nullptr, nullptr, BIG,
      20, 640, 1024, 640, 640, 0, XPB, FB2, 1);
  // ---- FFT stage 2 (K=640 folded): U = Xc@C_d (rows<640), W = Xs@S_d ----
  k_gemm4<4, false, false><<<dim3(5, 10, 8), 256, 0, stream>>>(
      Xcs, Xcs, Cb, Sb, Uw, nullptr, nullptr, nullptr, BIG,
      20, 640, 640, 1024, 640, FB2, 0, FB2, 1);
  // ---- finalize dual fold + fused RMSNorm#1: Y (=d_out f32) and xn ----
  k_fftfin<<<dim3(8192), 256, 0, stream>>>(Uw, ans, outF, xn);

  // ---- attention branch (V^T fused into qkv epilogue for cols >= 2048) ----
  k_gemm4<4, false, false><<<dim3(24, 64, 1), 256, 0, stream>>>(
      xn, xn, wqkvt, wqkvt, qkv, bqkv, nullptr, vtg, 2048,
      32, BIG, 1024, 1024, 3072, 0, 0, 0, 1);
  k_attn2<<<dim3(4, 128), 512, 0, stream>>>(qkv, vtg, Obuf);
  k_gemm4<4, false, false><<<dim3(8, 64, 1), 256, 0, stream>>>(
      Obuf, Obuf, wot, wot, d_out, bo, outF, nullptr, BIG,
      32, BIG, 1024, 1024, 1024, 0, 0, 0, 0);

  // ---- FFN branch (SiLU fused into uv GEMM; uv and wout at MR=8) ----
  k_rmsnorm<<<dim3(8192), 256, 0, stream>>>(outF, fns, xn2);
  k_gemm4<8, true, false><<<dim3(32, 32, 1), 256, 0, stream>>>(
      xn2, xn2, wuvt, wuvt, g, nullptr, nullptr, nullptr, BIG,
      32, BIG, 1024, 1024, 2048, 0, 0, 0, 1);
  k_gemm4<8, false, false><<<dim3(8, 32, 1), 256, 0, stream>>>(
      g, g, woutt, woutt, d_out, nullptr, outF, nullptr, BIG,
      64, BIG, 2048, 2048, 1024, 0, 0, 0, 0);
}

// Round 19
// 376.482 us; speedup vs baseline: 1.0533x; 1.0533x over previous
//
#include <hip/hip_runtime.h>
#include <stdint.h>

typedef unsigned short u16;
typedef __attribute__((ext_vector_type(8))) __bf16 bf16x8;
typedef __attribute__((ext_vector_type(4))) float f32x4;
typedef __attribute__((ext_vector_type(8))) u16 u16x8;

static __device__ __forceinline__ u16 f2bf(float f){
  uint32_t x = __builtin_bit_cast(uint32_t, f);
  x = (x + 0x7FFFu + ((x >> 16) & 1u)) >> 16;
  return (u16)x;
}
static __device__ __forceinline__ u16 f2bf_fast(float f){ // round-half-up (p>=0)
  uint32_t x = __builtin_bit_cast(uint32_t, f);
  return (u16)((x + 0x8000u) >> 16);
}
static __device__ __forceinline__ float bf2f(u16 h){
  uint32_t x = ((uint32_t)h) << 16;
  return __builtin_bit_cast(float, x);
}
static __device__ __forceinline__ f32x4 mfma16(bf16x8 a, bf16x8 b, f32x4 c){
  return __builtin_amdgcn_mfma_f32_16x16x32_bf16(a, b, c, 0, 0, 0);
}
// async global->LDS, 16B per lane; LDS dest = wave-uniform base + lane*16
static __device__ __forceinline__ void gload16(const void* g, void* l){
  __builtin_amdgcn_global_load_lds(
      (const __attribute__((address_space(1))) void*)(uintptr_t)g,
      (__attribute__((address_space(3))) void*)(uint32_t)(uintptr_t)l,
      16, 0, 0);
}

// ================================================================================
// k_prep — ALL prep work in one launch (block-range dispatch):
//  [0,1024)        DFT tables C=cos, S=sin (1024x1024 bf16)
//  [1024,4224)     x DOUBLE-fold transpose (real-DFT fold on BOTH n and d)
//  [4224,8320)     wq,wk,wv,wo transpose->bf16 (1024 blocks each)
//  [8320,12416)    wuv transpose + u/v 16-col interleave
//  [12416,14464)   wout transpose (2048x1024 -> 1024x2048)
//  [14464,14476)   bias concat (bq|bk|bv)
// ================================================================================
__global__ __launch_bounds__(256) void k_prep(
    const float* __restrict__ x,  const float* __restrict__ wq,
    const float* __restrict__ wk, const float* __restrict__ wv,
    const float* __restrict__ wo, const float* __restrict__ wuv,
    const float* __restrict__ wout,
    const float* __restrict__ bq, const float* __restrict__ bk,
    const float* __restrict__ bv,
    u16* __restrict__ Cb, u16* __restrict__ Sb,
    u16* __restrict__ xP, u16* __restrict__ xM,
    u16* __restrict__ wqkvt, u16* __restrict__ wot, u16* __restrict__ wuvt,
    u16* __restrict__ woutt, float* __restrict__ bqkv)
{
  int bid = blockIdx.x;
  int t = threadIdx.x;
  __shared__ float tA[32][33];
  __shared__ float tB[32][33];
  __shared__ float tC[32][33];
  __shared__ float tD[32][33];
  if (bid < 1024){                       // ---- twiddle tables ----
    int n = bid, m0 = t * 4;
    #pragma unroll
    for (int i = 0; i < 4; ++i){
      int m = m0 + i;
      int ph = (n * m) & 1023;
      float a = (float)ph * (1.0f / 512.0f);
      int idx = n * 1024 + m;
      Cb[idx] = f2bf(cospif(a)); Sb[idx] = f2bf(sinpif(a));
    }
    return;
  }
  bid -= 1024;
  if (bid >= 13440){                     // ---- bias concat (12 blocks) ----
    int i = (bid - 13440) * 256 + t;     // 0..3071
    bqkv[i] = i < 1024 ? bq[i] : (i < 2048 ? bk[i - 1024] : bv[i - 2048]);
    return;
  }
  int lx = t & 31, ly = t >> 5;
  if (bid < 3200){                       // ---- x double-fold transpose ----
    int z = bid / 400, rem = bid % 400;
    int dt = rem / 20, nt = rem % 20;    // output tile coords (d, n)
    int d0 = dt * 32, n0 = nt * 32;
    const float* ip = x + ((int64_t)z << 20);
    #pragma unroll
    for (int k8 = 0; k8 < 32; k8 += 8)
      tA[ly + k8][lx] = ip[(int64_t)(n0 + ly + k8) * 1024 + d0 + lx];
    if (dt <= 15){
      #pragma unroll
      for (int k8 = 0; k8 < 32; k8 += 8){
        float v = 0.f;
        if (!(d0 == 0 && lx == 31))
          v = ip[(int64_t)(n0 + ly + k8) * 1024 + (993 - d0 + lx)];
        tB[ly + k8][lx] = v;
      }
    }
    if (nt <= 15){
      #pragma unroll
      for (int k8 = 0; k8 < 32; k8 += 8){
        float v = 0.f;
        if (!(n0 == 0 && (ly + k8) == 31))
          v = ip[(int64_t)(993 - n0 + ly + k8) * 1024 + d0 + lx];
        tC[ly + k8][lx] = v;
      }
    }
    if (dt <= 15 && nt <= 15){
      #pragma unroll
      for (int k8 = 0; k8 < 32; k8 += 8){
        float v = 0.f;
        if (!(n0 == 0 && (ly + k8) == 31) && !(d0 == 0 && lx == 31))
          v = ip[(int64_t)(993 - n0 + ly + k8) * 1024 + (993 - d0 + lx)];
        tD[ly + k8][lx] = v;
      }
    }
    __syncthreads();
    u16* Pp = xP + (int64_t)z * 409600 + n0 + lx;
    u16* Mp = xM + (int64_t)z * 409600 + n0 + lx;
    #pragma unroll
    for (int k8 = 0; k8 < 32; k8 += 8){
      int dj = ly + k8;
      int d = d0 + dj, n = n0 + lx;
      bool dv = (d >= 1 && d <= 511), nv = (n >= 1 && n <= 511);
      float base = tA[lx][dj];
      float dm = dv ? tB[lx][31 - dj] : 0.f;
      float nm = nv ? tC[31 - lx][dj] : 0.f;
      float bm = (dv && nv) ? tD[31 - lx][31 - dj] : 0.f;
      float pv = base + dm + nm + bm;
      float mv = base - dm - nm + bm;
      if (d > 512 || n > 512){ pv = 0.f; mv = 0.f; }
      Pp[(int64_t)d * 640] = f2bf(pv);
      Mp[(int64_t)d * 640] = f2bf(mv);
    }
    return;
  }
  // ---- transpose jobs ----
  const float* in; u16* out; int Cc, R, bx, by;
  int64_t outOff = 0;
  bool uvperm = false;
  if (bid < 7296){                       // wq/wk/wv/wo
    int j = (bid - 3200) >> 10, tile = (bid - 3200) & 1023;
    const float* srcs[4] = {wq, wk, wv, wo};
    in = srcs[j]; Cc = 1024; R = 1024;
    if (j < 3){ out = wqkvt; outOff = (int64_t)j << 20; }
    else      { out = wot; }
    bx = tile & 31; by = tile >> 5;
  } else if (bid < 11392){               // wuv interleave (16-col groups)
    int tile = bid - 7296;
    in = wuv; out = wuvt; Cc = 4096; R = 1024; uvperm = true;
    bx = tile & 127; by = tile >> 7;
  } else {                               // wout
    int tile = bid - 11392;
    in = wout; out = woutt; Cc = 1024; R = 2048;
    bx = tile & 31; by = tile >> 5;
  }
  int tc = bx * 32, tr = by * 32;
  #pragma unroll
  for (int i = 0; i < 32; i += 8)
    tA[ly + i][lx] = in[(int64_t)(tr + ly + i) * Cc + tc + lx];
  __syncthreads();
  if (uvperm){
    #pragma unroll
    for (int i = 0; i < 32; i += 8){
      int c = tc + ly + i;
      int pr = (c < 2048) ? ((c >> 4) * 32 + (c & 15))
                          : (((c - 2048) >> 4) * 32 + 16 + ((c - 2048) & 15));
      out[(int64_t)pr * 1024 + tr + lx] = f2bf(tA[lx][ly + i]);
    }
  } else {
    u16* op = out + outOff;
    #pragma unroll
    for (int i = 0; i < 32; i += 8)
      op[(int64_t)(tc + ly + i) * R + tr + lx] = f2bf(tA[lx][ly + i]);
  }
}

// ---------------- RMSNorm (row=1024 f32) -> bf16 --------------------------------
__global__ __launch_bounds__(256) void k_rmsnorm(const float* __restrict__ x,
                                                 const float* __restrict__ sc,
                                                 u16* __restrict__ out){
  int r = blockIdx.x;
  const float4* px = (const float4*)(x + (int64_t)r * 1024);
  float4 v = px[threadIdx.x];
  float ss = v.x*v.x + v.y*v.y + v.z*v.z + v.w*v.w;
  #pragma unroll
  for (int o = 1; o < 64; o <<= 1) ss += __shfl_xor(ss, o);
  __shared__ float red[4];
  if ((threadIdx.x & 63) == 0) red[threadIdx.x >> 6] = ss;
  __syncthreads();
  float tot = red[0] + red[1] + red[2] + red[3];
  float rs = rsqrtf(tot * (1.0f / 1024.0f) + 1e-5f);
  float4 s4 = ((const float4*)sc)[threadIdx.x];
  ushort4 ov;
  ov.x = f2bf(v.x * rs * s4.x); ov.y = f2bf(v.y * rs * s4.y);
  ov.z = f2bf(v.z * rs * s4.z); ov.w = f2bf(v.w * rs * s4.w);
  ((ushort4*)(out + (int64_t)r * 1024))[threadIdx.x] = ov;
}

// ------- FFT finalize + fused RMSNorm: dual-fold (f_n rows AND f_d cols) --------
__global__ __launch_bounds__(256) void k_fftfin(const u16* __restrict__ Uw,
                                                const float* __restrict__ sc,
                                                float* __restrict__ Y,
                                                u16* __restrict__ xn){
  int row = blockIdx.x;            // b*1024 + k  (k = f_n)
  int b = row >> 10, k = row & 1023;
  int kp = (k <= 512) ? k : 1024 - k;
  float sm = (k <= 512) ? 1.0f : -1.0f;
  const u16* ub = Uw + (int64_t)b * 819200 + (int64_t)kp * 640;
  const u16* wb = ub + 640 * 640;
  int c0 = threadIdx.x * 4;
  float y[4];
  #pragma unroll
  for (int i = 0; i < 4; ++i){
    int c = c0 + i;
    int tp = (c <= 512) ? c : 1024 - c;
    float st = (c <= 512) ? sm : -sm;
    y[i] = bf2f(ub[tp]) - st * bf2f(wb[tp]);
  }
  float ss = y[0]*y[0] + y[1]*y[1] + y[2]*y[2] + y[3]*y[3];
  #pragma unroll
  for (int o = 1; o < 64; o <<= 1) ss += __shfl_xor(ss, o);
  __shared__ float red[4];
  if ((threadIdx.x & 63) == 0) red[threadIdx.x >> 6] = ss;
  __syncthreads();
  float tot = red[0] + red[1] + red[2] + red[3];
  float rs = rsqrtf(tot * (1.0f / 1024.0f) + 1e-5f);
  float4 s4 = ((const float4*)sc)[threadIdx.x];
  float4 yo; yo.x = y[0]; yo.y = y[1]; yo.z = y[2]; yo.w = y[3];
  ((float4*)(Y + (int64_t)row * 1024))[threadIdx.x] = yo;
  ushort4 ov;
  ov.x = f2bf(y[0] * rs * s4.x); ov.y = f2bf(y[1] * rs * s4.y);
  ov.z = f2bf(y[2] * rs * s4.z); ov.w = f2bf(y[3] * rs * s4.w);
  ((ushort4*)(xn + (int64_t)row * 1024))[threadIdx.x] = ov;
}

// ================================================================================
// bf16 GEMM — (MR*32) x 128 tile, BK=32, 256 thr (4 waves, 2x2 of (MR*16)x64).
// MR=4: proven m97 geometry, 32KB LDS dbuf, 4 blocks/CU.
// MR=8: 256x128 register-reuse tile (12 LDS reads : 32 MFMAs/wave), 48KB LDS,
//       ~2 waves/SIMD — used where the LDS-BW cap dominates (uv GEMM only).
// Bijective XCD swizzle (m204) + L2 supertile decode (GW=16/8/gx).
// COLCHUNK: column-major decode (FFT1). Zero-conflict row-pair LDS swizzle.
// Row-region operand select. Optional SiLU epilogue; optional fused V-transpose.
// ================================================================================
template<int MR, bool SILU, bool COLCHUNK>
__global__ __launch_bounds__(256, (MR == 8) ? 2 : 4) void k_gemm4(
    const u16* __restrict__ A0, const u16* __restrict__ A1,
    const u16* __restrict__ B0, const u16* __restrict__ B1,
    void* Cout, const float* __restrict__ bias, const float* resid,
    u16* __restrict__ vtbuf, int vtn0,
    int nkt, int rowSplit, int lda, int ldb, int ldc,
    int64_t aB, int64_t bB, int64_t cB, int outBf16)
{
  constexpr int BM = MR * 32;
  constexpr int ABUF = BM * 64;          // A K-tile bytes (BM x 32 x 2B)
  constexpr int BUFB = ABUF + 8192;      // + B K-tile (128 x 32 x 2B)
  constexpr int APASS = ABUF / 4096;     // A gloads per thread (2 or 4)
  __shared__ char smem[2 * BUFB];

  int z = blockIdx.z;
  // bijective XCD swizzle (m204): works for any nwg
  int nwg = gridDim.x * gridDim.y;
  int bid = blockIdx.y * gridDim.x + blockIdx.x;
  int q = nwg >> 3, r = nwg & 7, xc = bid & 7, off = bid >> 3;
  int sw = (xc < r ? xc * (q + 1) : r * (q + 1) + (xc - r) * q) + off;
  int bx, by;
  if (COLCHUNK){
    bx = sw / gridDim.y; by = sw % gridDim.y;
  } else {
    int gx = gridDim.x;
    int GW = ((gx & 15) == 0) ? 16 : (((gx & 7) == 0) ? 8 : gx);
    int gsz = GW * gridDim.y;
    int grp = sw / gsz, rem = sw % gsz;
    bx = grp * GW + rem % GW;
    by = rem / GW;
  }

  int tm = by * BM, tn = bx * 128;
  int tid = threadIdx.x;
  int lane = tid & 63, w = tid >> 6;
  int lr = lane & 15, lg = lane >> 4;
  int wOffM = (w >> 1) * (BM / 2), wOffN = (w & 1) * 64;

  const u16* Ap = ((tm < rowSplit) ? A0 : A1) + (int64_t)z * aB;
  const u16* Bp = ((tm < rowSplit) ? B0 : B1) + (int64_t)z * bB;
  int64_t cOff = (int64_t)z * cB;

  // staging decode: APASS A gloads + 2 B gloads of 16B per thread per K-tile
  const u16* pA[APASS];
  const u16* pB[2];
  #pragma unroll
  for (int p = 0; p < APASS; ++p){
    int D = tid * 16 + p * 4096, line = D >> 7, sp = ((D >> 4) & 7) ^ (line & 7);
    int rr = line * 2 + (sp >> 2), kg = sp & 3;
    pA[p] = Ap + (int64_t)(tm + rr) * lda + kg * 8;
  }
  #pragma unroll
  for (int p = 0; p < 2; ++p){
    int D = tid * 16 + p * 4096, line = D >> 7, sp = ((D >> 4) & 7) ^ (line & 7);
    int rr = line * 2 + (sp >> 2), kg = sp & 3;
    pB[p] = Bp + (int64_t)(tn + rr) * ldb + kg * 8;
  }

  int slotR = (lg + ((lr & 1) << 2)) ^ ((lr >> 1) & 7);
  int aRB = ((wOffM >> 1) + (lr >> 1)) * 128 + slotR * 16;
  int bRB = ((wOffN >> 1) + (lr >> 1)) * 128 + slotR * 16;

  const f32x4 fz = {0.f, 0.f, 0.f, 0.f};
  f32x4 acc[MR][4];
  #pragma unroll
  for (int i = 0; i < MR; ++i)
    #pragma unroll
    for (int j = 0; j < 4; ++j) acc[i][j] = fz;

  auto STAGE = [&](int kt, int bf){
    int k0 = kt * 32;
    char* d = smem + bf * BUFB + tid * 16;
    #pragma unroll
    for (int p = 0; p < APASS; ++p) gload16(pA[p] + k0, d + p * 4096);
    #pragma unroll
    for (int p = 0; p < 2; ++p) gload16(pB[p] + k0, d + ABUF + p * 4096);
  };
  auto COMPUTE = [&](const char* Ab){
    const char* Bb = Ab + ABUF;
    bf16x8 af[MR], bfr[4];
    #pragma unroll
    for (int i = 0; i < MR; ++i) af[i] = *(const bf16x8*)(Ab + aRB + i * 1024);
    #pragma unroll
    for (int j = 0; j < 4; ++j) bfr[j] = *(const bf16x8*)(Bb + bRB + j * 1024);
    #pragma unroll
    for (int i = 0; i < MR; ++i)
      #pragma unroll
      for (int j = 0; j < 4; ++j)
        acc[i][j] = mfma16(af[i], bfr[j], acc[i][j]);
  };

  STAGE(0, 0);
  __syncthreads();
  for (int kt = 0; kt < nkt; kt += 2){     // nkt always even
    STAGE(kt + 1, 1);
    COMPUTE(smem);
    __syncthreads();
    if (kt + 2 < nkt) STAGE(kt + 2, 0);
    COMPUTE(smem + BUFB);
    __syncthreads();
  }

  // ---- epilogue: C frag layout row=(lane>>4)*4+jj, col=lane&15 ----
  if constexpr (SILU){
    int colBase = ((tn + wOffN) >> 1) + lr;
    #pragma unroll
    for (int i = 0; i < MR; ++i){
      #pragma unroll
      for (int jj = 0; jj < 4; ++jj){
        int row = tm + wOffM + i * 16 + lg * 4 + jj;
        #pragma unroll
        for (int jp = 0; jp < 2; ++jp){
          float u = acc[i][jp * 2][jj], v = acc[i][jp * 2 + 1][jj];
          float s = u / (1.0f + __expf(-u));
          ((u16*)Cout)[(int64_t)row * ldc + colBase + jp * 16] = f2bf(s * v);
        }
      }
    }
    return;
  }
  if (vtbuf && tn >= vtn0){
    // V region of qkv: write transposed vt[b*16+h][d][key], 4 keys per ushort4
    int b = tm >> 10;
    int key0 = (tm & 1023) + wOffM + lg * 4;
    #pragma unroll
    for (int j = 0; j < 4; ++j){
      int col = tn + wOffN + j * 16 + lr;
      int hv = (col - 2048) >> 6, d = (col - 2048) & 63;
      float badd = bias ? bias[col] : 0.0f;
      u16* vb = vtbuf + ((int64_t)(b * 16 + hv) << 16) + d * 1024;
      #pragma unroll
      for (int i = 0; i < MR; ++i){
        ushort4 pk;
        pk.x = f2bf(acc[i][j][0] + badd);
        pk.y = f2bf(acc[i][j][1] + badd);
        pk.z = f2bf(acc[i][j][2] + badd);
        pk.w = f2bf(acc[i][j][3] + badd);
        *(ushort4*)(vb + key0 + i * 16) = pk;
      }
    }
    return;
  }
  #pragma unroll
  for (int i = 0; i < MR; ++i){
    #pragma unroll
    for (int j = 0; j < 4; ++j){
      int col = tn + wOffN + j * 16 + lr;
      float badd = bias ? bias[col] : 0.0f;
      #pragma unroll
      for (int jj = 0; jj < 4; ++jj){
        int row = tm + wOffM + i * 16 + lg * 4 + jj;
        int64_t idx = cOff + (int64_t)row * ldc + col;
        float v = acc[i][j][jj] + badd;
        if (resid) v += resid[idx];
        if (outBf16) ((u16*)Cout)[idx] = f2bf(v);
        else         ((float*)Cout)[idx] = v;
      }
    }
  }
}

// ---------------- flash attention v4: QBLK=256, 8 waves, static-max softmax -----
// grid (4 q-tiles of 256, 128 b*h), 512 thr; wave w owns 32 q-rows. 2 blocks/CU.
__global__ __launch_bounds__(512, 4) void k_attn2(const u16* __restrict__ qkv,
                                                  const u16* __restrict__ vt,
                                                  u16* __restrict__ O){
  __shared__ u16 Ks[2][4096];    // 16KB  [key][d] swizzled
  __shared__ u16 Vts[2][4096];   // 16KB  [d][key] swizzled
  __shared__ u16 Pl[8][2304];    // 36KB  per-wave P [32][72]
  int bh = blockIdx.y; int b = bh >> 4, h = bh & 15;
  int qt = blockIdx.x;
  int t = threadIdx.x, w = t >> 6, lane = t & 63, lr = lane & 15, lg = lane >> 4;
  int sr = t >> 3, sl = t & 7;           // staging: row 0..63, 16B slot
  int swz = (sl ^ (sr & 7)) * 8;         // swizzled k/key element offset

  const u16* kg = qkv + (int64_t)b * 1024 * 3072 + 1024 + h * 64;
  const u16* vg = vt + (int64_t)bh * 65536;

  const u16* qrow = qkv + (int64_t)(b * 1024 + qt * 256 + w * 32 + lr) * 3072 + h * 64;
  bf16x8 aq[2][2];
  #pragma unroll
  for (int m = 0; m < 2; ++m)
    #pragma unroll
    for (int kc = 0; kc < 2; ++kc)
      aq[m][kc] = *(const bf16x8*)(qrow + (int64_t)m * 16 * 3072 + kc * 32 + lg * 8);

  const f32x4 fz = {0.f, 0.f, 0.f, 0.f};
  f32x4 o_[2][4];
  float lj[2][4];
  #pragma unroll
  for (int m = 0; m < 2; ++m){
    #pragma unroll
    for (int d = 0; d < 4; ++d) o_[m][d] = fz;
    #pragma unroll
    for (int j = 0; j < 4; ++j) lj[m][j] = 0.f;
  }

  #define STAGE(ktile, bn) do {                                                   \
    gload16(kg + (int64_t)((ktile) * 64 + sr) * 3072 + swz,                       \
            (char*)Ks + (bn) * 8192 + t * 16);                                    \
    gload16(vg + (int64_t)sr * 1024 + (ktile) * 64 + swz,                         \
            (char*)Vts + (bn) * 8192 + t * 16);                                   \
  } while (0)

  STAGE(0, 0);
  __syncthreads();
  int buf = 0;
  int lsw = lr & 7;

  const float CSC = 0.1803368801111204f;  // log2(e)/8
  const float MSH = 8.656170245333781f;   // 6*log2(e): static shift

  #pragma unroll 1
  for (int kt = 0; kt < 16; ++kt){
    if (kt < 15) STAGE(kt + 1, buf ^ 1);

    f32x4 s[2][4];
    #pragma unroll
    for (int m = 0; m < 2; ++m)
      #pragma unroll
      for (int n = 0; n < 4; ++n) s[m][n] = fz;
    #pragma unroll
    for (int n = 0; n < 4; ++n){
      #pragma unroll
      for (int kc = 0; kc < 2; ++kc){
        bf16x8 kb = *(const bf16x8*)&Ks[buf][(n * 16 + lr) * 64 + (((kc * 4 + lg) ^ lsw) * 8)];
        s[0][n] = mfma16(aq[0][kc], kb, s[0][n]);
        s[1][n] = mfma16(aq[1][kc], kb, s[1][n]);
      }
    }

    #pragma unroll
    for (int m = 0; m < 2; ++m){
      #pragma unroll
      for (int j = 0; j < 4; ++j){
        float p0 = exp2f(fmaf(s[m][0][j], CSC, -MSH));
        float p1 = exp2f(fmaf(s[m][1][j], CSC, -MSH));
        float p2 = exp2f(fmaf(s[m][2][j], CSC, -MSH));
        float p3 = exp2f(fmaf(s[m][3][j], CSC, -MSH));
        lj[m][j] += (p0 + p1) + (p2 + p3);
        u16* pb = &Pl[w][(m * 16 + lg * 4 + j) * 72 + lr];
        pb[0]  = f2bf_fast(p0); pb[16] = f2bf_fast(p1);
        pb[32] = f2bf_fast(p2); pb[48] = f2bf_fast(p3);
      }
    }
    asm volatile("s_waitcnt lgkmcnt(0)" ::: "memory");
    __builtin_amdgcn_sched_barrier(0);

    #pragma unroll
    for (int kc = 0; kc < 2; ++kc){
      bf16x8 pa0 = *(const bf16x8*)&Pl[w][(lr) * 72 + kc * 32 + lg * 8];
      bf16x8 pa1 = *(const bf16x8*)&Pl[w][(16 + lr) * 72 + kc * 32 + lg * 8];
      #pragma unroll
      for (int dt = 0; dt < 4; ++dt){
        bf16x8 vb = *(const bf16x8*)&Vts[buf][(dt * 16 + lr) * 64 + (((kc * 4 + lg) ^ lsw) * 8)];
        o_[0][dt] = mfma16(pa0, vb, o_[0][dt]);
        o_[1][dt] = mfma16(pa1, vb, o_[1][dt]);
      }
    }
    __syncthreads();
    buf ^= 1;
  }
  #undef STAGE

  u16* obase = O + (int64_t)(b * 1024 + qt * 256 + w * 32) * 1024 + h * 64;
  #pragma unroll
  for (int m = 0; m < 2; ++m){
    #pragma unroll
    for (int j = 0; j < 4; ++j){
      float l = lj[m][j];
      l += __shfl_xor(l, 1); l += __shfl_xor(l, 2);
      l += __shfl_xor(l, 4); l += __shfl_xor(l, 8);
      float inv = 1.0f / l;
      int q = m * 16 + lg * 4 + j;
      #pragma unroll
      for (int dt = 0; dt < 4; ++dt)
        obase[(int64_t)q * 1024 + dt * 16 + lr] = f2bf(o_[m][dt][j] * inv);
    }
  }
}

// ================================================================================
extern "C" void kernel_launch(void* const* d_in, const int* in_sizes, int n_in,
                              void* d_out, int out_size, void* d_ws, size_t ws_size,
                              hipStream_t stream)
{
  (void)in_sizes; (void)n_in; (void)out_size; (void)ws_size;
  const float* x    = (const float*)d_in[0];
  const float* ans  = (const float*)d_in[1];
  const float* fns  = (const float*)d_in[2];
  const float* wq   = (const float*)d_in[3];
  const float* bq   = (const float*)d_in[4];
  const float* wk   = (const float*)d_in[5];
  const float* bk   = (const float*)d_in[6];
  const float* wv   = (const float*)d_in[7];
  const float* bvv  = (const float*)d_in[8];
  const float* wo   = (const float*)d_in[9];
  const float* bo   = (const float*)d_in[10];
  const float* wuv  = (const float*)d_in[11];
  const float* wout = (const float*)d_in[12];

  char* ws = (char*)d_ws;
  const size_t MB = 1u << 20;
  const int64_t XPB = 409600;                    // per-batch P/M elems (640x640)
  const int64_t FB2 = (int64_t)1280 * 640;       // per-batch Xcs/Uw (folded cols)
  const int BIG = 1 << 30;
  // arena (peak ~128.01 MB, lifetime-based reuse)
  u16*  xP    = (u16*)(ws + 0 * MB);      // 6.6MB even-even fold, dies after FFT1
  u16*  xM    = (u16*)(ws + 7 * MB);      // 6.6MB odd-odd fold, dies after FFT1
  u16*  Xcs   = (u16*)(ws + 14 * MB);     // 13.1MB folded FFT1 out, dies at FFT2
  u16*  Uw    = (u16*)(ws + 28 * MB);     // 13.1MB FFT2 out, dies at fftfin
  u16*  xn    = (u16*)(ws + 56 * MB);     // 16MB  RMSNorm#1 out (fused in fftfin)
  u16*  qkv   = (u16*)(ws + 0 * MB);      // 48MB  (reuses xP/xM/Xcs/Uw post-fftfin)
  u16*  vtg   = (u16*)(ws + 72 * MB);     // 16MB  V^T (written by qkv GEMM)
  u16*  Obuf  = (u16*)(ws + 88 * MB);     // 16MB  (attn out)
  u16*  xn2   = (u16*)(ws + 0 * MB);      // 16MB  (after wo; qkv dead)
  u16*  g     = (u16*)(ws + 16 * MB);     // 32MB
  u16*  Cb    = (u16*)(ws + 104 * MB);    // 2MB
  u16*  Sb    = (u16*)(ws + 106 * MB);    // 2MB
  u16*  wqkvt = (u16*)(ws + 108 * MB);    // 6MB
  u16*  wot   = (u16*)(ws + 114 * MB);    // 2MB
  u16*  wuvt  = (u16*)(ws + 116 * MB);    // 8MB  (interleaved u/v layout)
  u16*  woutt = (u16*)(ws + 124 * MB);    // 4MB
  float* bqkv = (float*)(ws + 128 * MB);  // 12KB
  float* outF = (float*)d_out;            // Y lives in d_out (f32 residual)

  // ---- fused prep (tables + x double-fold + weight transposes + bias) ----
  k_prep<<<dim3(14476), 256, 0, stream>>>(x, wq, wk, wv, wo, wuv, wout,
      bq, bk, bvv, Cb, Sb, xP, xM, wqkvt, wot, wuvt, woutt, bqkv);

  // ---- FFT stage 1 (both axes folded): Xcs[b][1280][640], K=640 ----
  k_gemm4<4, false, true><<<dim3(5, 10, 8), 256, 0, stream>>>(
      Cb, Sb - 640 * 1024, xP, xM, Xcs, nullptr, nullptr, nullptr, BIG,
      20, 640, 1024, 640, 640, 0, XPB, FB2, 1);
  // ---- FFT stage 2 (K=640 folded): U = Xc@C_d (rows<640), W = Xs@S_d ----
  k_gemm4<4, false, false><<<dim3(5, 10, 8), 256, 0, stream>>>(
      Xcs, Xcs, Cb, Sb, Uw, nullptr, nullptr, nullptr, BIG,
      20, 640, 640, 1024, 640, FB2, 0, FB2, 1);
  // ---- finalize dual fold + fused RMSNorm#1: Y (=d_out f32) and xn ----
  k_fftfin<<<dim3(8192), 256, 0, stream>>>(Uw, ans, outF, xn);

  // ---- attention branch (V^T fused into qkv epilogue for cols >= 2048) ----
  k_gemm4<4, false, false><<<dim3(24, 64, 1), 256, 0, stream>>>(
      xn, xn, wqkvt, wqkvt, qkv, bqkv, nullptr, vtg, 2048,
      32, BIG, 1024, 1024, 3072, 0, 0, 0, 1);
  k_attn2<<<dim3(4, 128), 512, 0, stream>>>(qkv, vtg, Obuf);
  k_gemm4<4, false, false><<<dim3(8, 64, 1), 256, 0, stream>>>(
      Obuf, Obuf, wot, wot, d_out, bo, outF, nullptr, BIG,
      32, BIG, 1024, 1024, 1024, 0, 0, 0, 0);

  // ---- FFN branch (SiLU fused into uv GEMM; uv at MR=8, wout at MR=4) ----
  k_rmsnorm<<<dim3(8192), 256, 0, stream>>>(outF, fns, xn2);
  k_gemm4<8, true, false><<<dim3(32, 32, 1), 256, 0, stream>>>(
      xn2, xn2, wuvt, wuvt, g, nullptr, nullptr, nullptr, BIG,
      32, BIG, 1024, 1024, 2048, 0, 0, 0, 1);
  k_gemm4<4, false, false><<<dim3(8, 64, 1), 256, 0, stream>>>(
      g, g, woutt, woutt, d_out, nullptr, outF, nullptr, BIG,
      64, BIG, 2048, 2048, 1024, 0, 0, 0, 0);
}